// Round 11
// baseline (436.018 us; speedup 1.0000x reference)
//
#include <hip/hip_runtime.h>
#include <hip/hip_bf16.h>
#include <math.h>

// ---------------- problem constants ----------------
#define NB 4
#define NH 96
#define NW 96
#define ND 768
#define NPIX (NH*NW)          // 9216
#define RR 3
#define NK 49
#define DCC 32                // K per staged chunk
#define NCH 24                // 768/32 — full K per block (fused, NS=1)
#define TSX 16                // tile 16 wide
#define TSY 4                 //        4 tall (wave per row)
#define HLX 22                // halo 22 wide
#define HLY 10                // halo 10 tall
#define NVIS (HLX*HLY)        // 220
#define VPAD 224              // vis region padded to multiple of 32
#define NSLOT (VPAD+64)       // 288 (224 vis+dummy, 64 rubin)
#define LROW 40               // ushorts per slot (32 bf16 + 8 pad = 80B)
#define NPASS 9               // 288 slots * 8 lanes / 256 threads
#define TPX 65                // transpose row stride (floats) — conflict-free
#define TBASE 512             // transpose region base (floats)
#define PBASE 4680            // softmax partials region base (floats)
#define TAU 0.1f
#define SCALE 0.03608439182435161f  // 1/sqrt(768)
#define UNI (1.0f/49.0f)

typedef float f32x4 __attribute__((ext_vector_type(4)));
typedef short bfx8 __attribute__((ext_vector_type(8)));

__device__ __forceinline__ unsigned pk2(float lo, float hi) {
  __hip_bfloat162 h = __float22bfloat162_rn(make_float2(lo, hi));  // v_cvt_pk_bf16_f32
  unsigned u; __builtin_memcpy(&u, &h, 4);
  return u;
}

// barrier that waits LDS ops only (no vmcnt drain — prefetch stays in flight)
#define BARRIER() do { asm volatile("s_waitcnt lgkmcnt(0)" ::: "memory"); \
                       __builtin_amdgcn_s_barrier(); } while (0)

// ws layout: dyl, dxl : float [b][NPIX] ; gacc : float [b][49][144]
// out: dra | ddec | conf_local | conf_global[4] | lw

// ---------------- fused kernel: MFMA correlation + norms + local softmax ----------------
__global__ __launch_bounds__(256, 4) void corr_fused(
    const float* __restrict__ rubin, const float* __restrict__ vis,
    float* __restrict__ dyl, float* __restrict__ dxl,
    float* __restrict__ gacc, float* __restrict__ out) {
  __shared__ __align__(16) unsigned short lds[NSLOT*LROW];  // 23,040 B (float view: 5760)
  float* ldsf = (float*)lds;
  const int tid = threadIdx.x;

  // ---- XCD-chunked swizzle: each XCD owns 72 contiguous (b,ty,tx) slots ----
  const int wg = blockIdx.x;                  // 0..575
  const int vs = (wg & 7) * 72 + (wg >> 3);   // bijective (576 = 8*72)
  const int b = vs / 144, t = vs % 144;
  const int tileY = t / 6, tileX = t % 6;

  const int g8 = tid >> 3, q = tid & 7;       // 32 slots/pass, 8 lanes/slot

  // ---- staging slot -> global element offset ----
  unsigned voff[NPASS]; int lws[NPASS];
  #pragma unroll
  for (int p = 0; p < NPASS; ++p) {
    const int s = p*32 + g8;
    lws[p] = s*LROW + q*4;
    unsigned pix = 0;
    if (p < 7) {                                 // vis halo (or dummy)
      const int vy = s / HLX, vx = s % HLX;
      const int gh = min(max(tileY*TSY + vy - RR, 0), NH-1);
      const int gw = min(max(tileX*TSX + vx - RR, 0), NW-1);
      pix = (unsigned)(b*NPIX + gh*NW + gw);
    } else {                                     // rubin
      const int ridx = s - VPAD;
      pix = (unsigned)(b*NPIX + (tileY*TSY + (ridx >> 4))*NW + tileX*TSX + (ridx & 15));
    }
    voff[p] = pix*ND + (unsigned)(q*4);
  }
  #define ACT(p) ((p) != 6 || g8 < 28)

  // ---- MFMA addressing: wave wv owns tile row wv ----
  const int lane = tid & 63, wv = tid >> 6;
  const int j15 = lane & 15, kq = lane >> 4;
  const int aOff = (VPAD + wv*TSX + j15)*LROW + kq*8;
  const int bO0 = j15*LROW + kq*8;
  const int bO1 = min(j15 + 16, HLX-1)*LROW + kq*8;

  f32x4 acc[7][2];
  #pragma unroll
  for (int dy = 0; dy < 7; ++dy) {
    acc[dy][0] = (f32x4){0.f,0.f,0.f,0.f};
    acc[dy][1] = (f32x4){0.f,0.f,0.f,0.f};
  }
  float ssq[NPASS];
  #pragma unroll
  for (int p = 0; p < NPASS; ++p) ssq[p] = 0.f;

#define LOADCH(Larr, chv) { \
  _Pragma("unroll") \
  for (int p = 0; p < NPASS; ++p) if (ACT(p)) \
    Larr[p] = (p < 7) ? *(const float4*)(vis   + voff[p] + (chv)*DCC) \
                      : *(const float4*)(rubin + voff[p] + (chv)*DCC); }

#define WRITECH(Larr) { \
  _Pragma("unroll") \
  for (int p = 0; p < NPASS; ++p) if (ACT(p)) { \
    const float4 v = Larr[p]; \
    ssq[p] += v.x*v.x + v.y*v.y + v.z*v.z + v.w*v.w; \
    *(uint2*)&lds[lws[p]] = make_uint2(pk2(v.x,v.y), pk2(v.z,v.w)); } }

#define MFMACH() { \
  const bfx8 A = *(const bfx8*)&lds[aOff]; \
  _Pragma("unroll") \
  for (int dy = 0; dy < 7; ++dy) { \
    const int rbase = (wv + dy)*HLX*LROW; \
    const bfx8 B0 = *(const bfx8*)&lds[rbase + bO0]; \
    const bfx8 B1 = *(const bfx8*)&lds[rbase + bO1]; \
    acc[dy][0] = __builtin_amdgcn_mfma_f32_16x16x32_bf16(A, B0, acc[dy][0], 0, 0, 0); \
    acc[dy][1] = __builtin_amdgcn_mfma_f32_16x16x32_bf16(A, B1, acc[dy][1], 0, 0, 0); } }

  // ---- 2-deep software pipeline (named reg sets — no runtime indexing) ----
  float4 LA[NPASS], LB[NPASS];
  LOADCH(LA, 0);
  LOADCH(LB, 1);
  for (int ch = 0; ch < NCH; ch += 2) {
    if (ch) BARRIER();            // prev odd chunk's MFMA readers done
    WRITECH(LA);
    BARRIER();
    if (ch + 2 < NCH) LOADCH(LA, ch + 2);   // in flight across MFMA + barrier + write
    MFMACH();
    BARRIER();                    // even chunk's MFMA readers done
    WRITECH(LB);
    BARRIER();
    if (ch + 3 < NCH) LOADCH(LB, ch + 3);
    MFMACH();
  }
  BARRIER();   // all MFMA LDS reads done before epilogue clobbers lds

  // ---- epilogue phase 1: per-slot sum-of-squares into ldsf[0..287] ----
  #pragma unroll
  for (int p = 0; p < NPASS; ++p) {
    float r = ACT(p) ? ssq[p] : 0.f;
    r += __shfl_xor(r, 1); r += __shfl_xor(r, 2); r += __shfl_xor(r, 4);
    if (q == 0 && ACT(p)) ldsf[p*32 + g8] = r;
  }
  BARRIER();

  // ---- epilogue phase 2: transpose C-fragments -> ldsf[TBASE + px*TPX + j] ----
  #pragma unroll
  for (int dy = 0; dy < 7; ++dy)
    #pragma unroll
    for (int h = 0; h < 2; ++h)
      #pragma unroll
      for (int r = 0; r < 4; ++r) {
        const int i = kq*4 + r;
        const int dxp3 = h ? (j15 + 16 - i) : (j15 - i);
        if (dxp3 >= 0 && dxp3 < 7)
          ldsf[TBASE + (wv*TSX + i)*TPX + dy*7 + dxp3] = acc[dy][h][r];
      }
  BARRIER();

  // ---- epilogue phase 3: wave-parallel softmax (wave wv owns 12-13 taps) ----
  {
    const int px = lane, rr = px >> 4, cc = px & 15;     // 64 pixels, all waves
    const float irf = (SCALE/TAU) / fmaxf(sqrtf(ldsf[VPAD + px]), 1e-6f);
    const int jstart = wv*12 + (wv > 0 ? 1 : 0);         // 13,12,12,12 taps
    const int jcnt = (wv == 0) ? 13 : 12;
    float tvv[13];
    float mx = -1e30f;
    #pragma unroll
    for (int jj = 0; jj < 13; ++jj) {
      if (jj < jcnt) {
        const int j = jstart + jj;
        const int jy = j / 7, jx = j % 7;
        const float c = ldsf[TBASE + px*TPX + j];
        const float iv = 1.f / fmaxf(sqrtf(ldsf[(rr+jy)*HLX + cc + jx]), 1e-6f);
        const float tv = c * irf * iv;
        tvv[jj] = tv;
        mx = fmaxf(mx, tv);
        float red = tv;                                   // tile-sum for global softmax
        #pragma unroll
        for (int m = 1; m < 64; m <<= 1) red += __shfl_xor(red, m);
        if (lane == 0) gacc[((size_t)b*NK + j)*144 + t] = red;
      } else tvv[jj] = -1e30f;
    }
    float s = 0.f, sy = 0.f, sx = 0.f;
    #pragma unroll
    for (int jj = 0; jj < 13; ++jj) {
      if (jj < jcnt) {
        const int j = jstart + jj;
        const float e = expf(tvv[jj] - mx);
        s += e; sy += e*(float)(j/7 - RR); sx += e*(float)(j%7 - RR);
      }
    }
    float* pp = &ldsf[PBASE + (wv*64 + px)*4];
    pp[0] = mx; pp[1] = s; pp[2] = sy; pp[3] = sx;
  }
  BARRIER();

  // ---- epilogue phase 4: combine wave partials (wave 0), write outputs ----
  if (wv == 0) {
    const int px = lane, rr = px >> 4, cc = px & 15;
    float M[4], S[4], SY[4], SX[4];
    #pragma unroll
    for (int w = 0; w < 4; ++w) {
      const float* pp = &ldsf[PBASE + (w*64 + px)*4];
      M[w] = pp[0]; S[w] = pp[1]; SY[w] = pp[2]; SX[w] = pp[3];
    }
    float m = fmaxf(fmaxf(M[0], M[1]), fmaxf(M[2], M[3]));
    float s = 0.f, sy = 0.f, sx = 0.f;
    #pragma unroll
    for (int w = 0; w < 4; ++w) {
      const float f = expf(M[w] - m);
      s += S[w]*f; sy += SY[w]*f; sx += SX[w]*f;
    }
    const float inv_s = 1.f / s;         // conf_local = exp(mx-mx)/s at the argmax
    const int n = (tileY*TSY + rr)*NW + tileX*TSX + cc;
    const int gg = b*NPIX + n;
    dyl[gg] = sy * inv_s;
    dxl[gg] = sx * inv_s;
    out[(size_t)2*NB*NPIX + gg] = inv_s;                       // conf_local
    const float lw = fminf(fmaxf((inv_s - UNI)/(1.f-UNI), 0.f), 1.f);
    out[(size_t)3*NB*NPIX + 4 + gg] = lw;                      // lw
  }
}

// ---------------- kernel E: global softmax (per-block recompute) + blend + smooth ----------------
__global__ __launch_bounds__(256) void smooth_global(
    const float* __restrict__ dyl, const float* __restrict__ dxl,
    const float* __restrict__ gacc, float* __restrict__ out,
    const int* __restrict__ hvisp, const int* __restrict__ wvisp) {
  __shared__ float sh[2];
  const int g = blockIdx.x*256 + threadIdx.x;
  const int b = g / NPIX, n = g % NPIX;
  const int h = n / NW, w = n % NW;

  // wave 0 recomputes this batch's global softmax (deterministic, identical across blocks)
  if (threadIdx.x < 64) {
    const int k = threadIdx.x;
    float t = -1e30f;
    if (k < NK) {
      float ssum = 0.f;
      for (int i = 0; i < 144; ++i) ssum += gacc[((size_t)b*NK + k)*144 + i];
      t = ssum * (1.f / (float)NPIX);
    }
    float m = t;
    #pragma unroll
    for (int msk = 1; msk < 64; msk <<= 1) m = fmaxf(m, __shfl_xor(m, msk));
    const float e = (k < NK) ? expf(t - m) : 0.f;
    const float dyv = (k < NK) ? (float)(k/7 - RR) : 0.f;
    const float dxv = (k < NK) ? (float)(k%7 - RR) : 0.f;
    float s = e, sy = e*dyv, sx = e*dxv;
    #pragma unroll
    for (int msk = 1; msk < 64; msk <<= 1) {
      s  += __shfl_xor(s,  msk);
      sy += __shfl_xor(sy, msk);
      sx += __shfl_xor(sx, msk);
    }
    if (k == 0) {
      out[(size_t)3*NB*NPIX + b] = 1.f / s;   // conf_global (same value from all 36 blocks of b)
      sh[0] = sy / s;                          // dy_global
      sh[1] = sx / s;                          // dx_global
    }
  }
  __syncthreads();
  const float dyg = sh[0], dxg = sh[1];

  const float* conf = out + (size_t)2*NB*NPIX;
  float sy = 0.f, sx = 0.f;
  #pragma unroll
  for (int ddy = -1; ddy <= 1; ++ddy)
    #pragma unroll
    for (int ddx = -1; ddx <= 1; ++ddx) {
      const int hh = h + ddy, wc = w + ddx;
      if (hh >= 0 && hh < NH && wc >= 0 && wc < NW) {   // zero padding
        const int q2 = b*NPIX + hh*NW + wc;
        const float cf = conf[q2];
        const float lw = fminf(fmaxf((cf - UNI)/(1.f-UNI), 0.f), 1.f);
        sy += lw*dyl[q2] + (1.f-lw)*dyg;
        sx += lw*dxl[q2] + (1.f-lw)*dxg;
      }
    }
  const float skyy = (float)hvisp[0] * 0.1f / (float)NH;
  const float skyx = (float)wvisp[0] * 0.1f / (float)NW;
  out[g] = sx * (1.f/9.f) * skyx;                     // dra
  out[(size_t)NB*NPIX + g] = sy * (1.f/9.f) * skyy;   // ddec
}

// ---------------- host launch ----------------
extern "C" void kernel_launch(void* const* d_in, const int* in_sizes, int n_in,
                              void* d_out, int out_size, void* d_ws, size_t ws_size,
                              hipStream_t stream) {
  (void)in_sizes; (void)n_in; (void)out_size; (void)ws_size;
  const float* rubin = (const float*)d_in[0];
  const float* vis   = (const float*)d_in[1];
  const int* hvis = (const int*)d_in[4];
  const int* wvis = (const int*)d_in[5];
  float* out = (float*)d_out;

  float* dyl  = (float*)d_ws;                       // NB*NPIX
  float* dxl  = dyl  + (size_t)NB*NPIX;             // NB*NPIX
  float* gacc = dxl  + (size_t)NB*NPIX;             // NB*49*144

  corr_fused<<<dim3(576), 256, 0, stream>>>(rubin, vis, dyl, dxl, gacc, out);
  smooth_global<<<dim3((NB*NPIX)/256), 256, 0, stream>>>(dyl, dxl, gacc, out, hvis, wvis);
}

// Round 12
// 78.286 us; speedup vs baseline: 5.5696x; 5.5696x over previous
//
#include <hip/hip_runtime.h>
#include <hip/hip_bf16.h>
#include <math.h>

// ---------------- problem constants ----------------
#define NB 4
#define NH 96
#define NW 96
#define ND 768
#define NPIX (NH*NW)          // 9216
#define RR 3
#define NK 49
#define DCC 32                // K per staged chunk
#define NCH 24                // 768/32 — full K per block (fused, NS=1)
#define TSX 16                // tile 16 wide
#define TSY 4                 //        4 tall (wave per row)
#define HLX 22                // halo 22 wide
#define HLY 10                // halo 10 tall
#define NVIS (HLX*HLY)        // 220
#define VPAD 224              // vis region padded to multiple of 32
#define NSLOT (VPAD+64)       // 288 (224 vis+dummy, 64 rubin)
#define LROW 40               // ushorts per slot (32 bf16 + 8 pad = 80B)
#define NPASS 9               // 288 slots * 8 lanes / 256 threads
#define TPX 65                // transpose row stride (floats) — conflict-free
#define TBASE 512             // transpose region base (floats)
#define PBASE 4680            // softmax partials region base (floats)
#define TAU 0.1f
#define SCALE 0.03608439182435161f  // 1/sqrt(768)
#define UNI (1.0f/49.0f)

typedef float f32x4 __attribute__((ext_vector_type(4)));
typedef short bfx8 __attribute__((ext_vector_type(8)));

__device__ __forceinline__ unsigned pk2(float lo, float hi) {
  __hip_bfloat162 h = __float22bfloat162_rn(make_float2(lo, hi));  // v_cvt_pk_bf16_f32
  unsigned u; __builtin_memcpy(&u, &h, 4);
  return u;
}

// barrier that waits LDS ops only (no vmcnt drain — prefetch stays in flight)
#define BARRIER() do { asm volatile("s_waitcnt lgkmcnt(0)" ::: "memory"); \
                       __builtin_amdgcn_s_barrier(); } while (0)

// ws layout: dyl, dxl : float [b][NPIX] ; gacc : float [b][49][144]
// out: dra | ddec | conf_local | conf_global[4] | lw

// ---------------- fused kernel: MFMA correlation + norms + local softmax ----------------
// NOTE: __launch_bounds__(256, 2) is load-bearing. The 2nd arg is min waves/SIMD:
// 2 -> 256-reg unified cap (fits ~108 VGPR + 56 acc). 4 -> 128-reg cap -> LA/LB
// spill to scratch -> 827 MB of TCC write traffic and 5x slowdown (measured r11).
__global__ __launch_bounds__(256, 2) void corr_fused(
    const float* __restrict__ rubin, const float* __restrict__ vis,
    float* __restrict__ dyl, float* __restrict__ dxl,
    float* __restrict__ gacc, float* __restrict__ out) {
  __shared__ __align__(16) unsigned short lds[NSLOT*LROW];  // 23,040 B (float view: 5760)
  float* ldsf = (float*)lds;
  const int tid = threadIdx.x;

  // ---- XCD-chunked swizzle: each XCD owns 72 contiguous (b,ty,tx) slots ----
  const int wg = blockIdx.x;                  // 0..575
  const int vs = (wg & 7) * 72 + (wg >> 3);   // bijective (576 = 8*72)
  const int b = vs / 144, t = vs % 144;
  const int tileY = t / 6, tileX = t % 6;

  const int g8 = tid >> 3, q = tid & 7;       // 32 slots/pass, 8 lanes/slot

  // ---- staging slot -> global element offset ----
  unsigned voff[NPASS]; int lws[NPASS];
  #pragma unroll
  for (int p = 0; p < NPASS; ++p) {
    const int s = p*32 + g8;
    lws[p] = s*LROW + q*4;
    unsigned pix = 0;
    if (p < 7) {                                 // vis halo (or dummy)
      const int vy = s / HLX, vx = s % HLX;
      const int gh = min(max(tileY*TSY + vy - RR, 0), NH-1);
      const int gw = min(max(tileX*TSX + vx - RR, 0), NW-1);
      pix = (unsigned)(b*NPIX + gh*NW + gw);
    } else {                                     // rubin
      const int ridx = s - VPAD;
      pix = (unsigned)(b*NPIX + (tileY*TSY + (ridx >> 4))*NW + tileX*TSX + (ridx & 15));
    }
    voff[p] = pix*ND + (unsigned)(q*4);
  }
  #define ACT(p) ((p) != 6 || g8 < 28)

  // ---- MFMA addressing: wave wv owns tile row wv ----
  const int lane = tid & 63, wv = tid >> 6;
  const int j15 = lane & 15, kq = lane >> 4;
  const int aOff = (VPAD + wv*TSX + j15)*LROW + kq*8;
  const int bO0 = j15*LROW + kq*8;
  const int bO1 = min(j15 + 16, HLX-1)*LROW + kq*8;

  f32x4 acc[7][2];
  #pragma unroll
  for (int dy = 0; dy < 7; ++dy) {
    acc[dy][0] = (f32x4){0.f,0.f,0.f,0.f};
    acc[dy][1] = (f32x4){0.f,0.f,0.f,0.f};
  }
  float ssq[NPASS];
  #pragma unroll
  for (int p = 0; p < NPASS; ++p) ssq[p] = 0.f;

#define LOADCH(Larr, chv) { \
  _Pragma("unroll") \
  for (int p = 0; p < NPASS; ++p) if (ACT(p)) \
    Larr[p] = (p < 7) ? *(const float4*)(vis   + voff[p] + (chv)*DCC) \
                      : *(const float4*)(rubin + voff[p] + (chv)*DCC); }

#define WRITECH(Larr) { \
  _Pragma("unroll") \
  for (int p = 0; p < NPASS; ++p) if (ACT(p)) { \
    const float4 v = Larr[p]; \
    ssq[p] += v.x*v.x + v.y*v.y + v.z*v.z + v.w*v.w; \
    *(uint2*)&lds[lws[p]] = make_uint2(pk2(v.x,v.y), pk2(v.z,v.w)); } }

#define MFMACH() { \
  const bfx8 A = *(const bfx8*)&lds[aOff]; \
  _Pragma("unroll") \
  for (int dy = 0; dy < 7; ++dy) { \
    const int rbase = (wv + dy)*HLX*LROW; \
    const bfx8 B0 = *(const bfx8*)&lds[rbase + bO0]; \
    const bfx8 B1 = *(const bfx8*)&lds[rbase + bO1]; \
    acc[dy][0] = __builtin_amdgcn_mfma_f32_16x16x32_bf16(A, B0, acc[dy][0], 0, 0, 0); \
    acc[dy][1] = __builtin_amdgcn_mfma_f32_16x16x32_bf16(A, B1, acc[dy][1], 0, 0, 0); } }

  // ---- 2-deep software pipeline (named reg sets — no runtime indexing) ----
  float4 LA[NPASS], LB[NPASS];
  LOADCH(LA, 0);
  LOADCH(LB, 1);
  for (int ch = 0; ch < NCH; ch += 2) {
    if (ch) BARRIER();            // prev odd chunk's MFMA readers done
    WRITECH(LA);
    BARRIER();
    if (ch + 2 < NCH) LOADCH(LA, ch + 2);   // in flight across MFMA + barrier + write
    MFMACH();
    BARRIER();                    // even chunk's MFMA readers done
    WRITECH(LB);
    BARRIER();
    if (ch + 3 < NCH) LOADCH(LB, ch + 3);
    MFMACH();
  }
  BARRIER();   // all MFMA LDS reads done before epilogue clobbers lds

  // ---- epilogue phase 1: per-slot sum-of-squares into ldsf[0..287] ----
  #pragma unroll
  for (int p = 0; p < NPASS; ++p) {
    float r = ACT(p) ? ssq[p] : 0.f;
    r += __shfl_xor(r, 1); r += __shfl_xor(r, 2); r += __shfl_xor(r, 4);
    if (q == 0 && ACT(p)) ldsf[p*32 + g8] = r;
  }
  BARRIER();

  // ---- epilogue phase 2: transpose C-fragments -> ldsf[TBASE + px*TPX + j] ----
  #pragma unroll
  for (int dy = 0; dy < 7; ++dy)
    #pragma unroll
    for (int h = 0; h < 2; ++h)
      #pragma unroll
      for (int r = 0; r < 4; ++r) {
        const int i = kq*4 + r;
        const int dxp3 = h ? (j15 + 16 - i) : (j15 - i);
        if (dxp3 >= 0 && dxp3 < 7)
          ldsf[TBASE + (wv*TSX + i)*TPX + dy*7 + dxp3] = acc[dy][h][r];
      }
  BARRIER();

  // ---- epilogue phase 3: wave-parallel softmax (wave wv owns 12-13 taps) ----
  {
    const int px = lane, rr = px >> 4, cc = px & 15;     // 64 pixels, all waves
    const float irf = (SCALE/TAU) / fmaxf(sqrtf(ldsf[VPAD + px]), 1e-6f);
    const int jstart = wv*12 + (wv > 0 ? 1 : 0);         // 13,12,12,12 taps
    const int jcnt = (wv == 0) ? 13 : 12;
    float tvv[13];
    float mx = -1e30f;
    #pragma unroll
    for (int jj = 0; jj < 13; ++jj) {
      if (jj < jcnt) {
        const int j = jstart + jj;
        const int jy = j / 7, jx = j % 7;
        const float c = ldsf[TBASE + px*TPX + j];
        const float iv = 1.f / fmaxf(sqrtf(ldsf[(rr+jy)*HLX + cc + jx]), 1e-6f);
        const float tv = c * irf * iv;
        tvv[jj] = tv;
        mx = fmaxf(mx, tv);
        float red = tv;                                   // tile-sum for global softmax
        #pragma unroll
        for (int m = 1; m < 64; m <<= 1) red += __shfl_xor(red, m);
        if (lane == 0) gacc[((size_t)b*NK + j)*144 + t] = red;
      } else tvv[jj] = -1e30f;
    }
    float s = 0.f, sy = 0.f, sx = 0.f;
    #pragma unroll
    for (int jj = 0; jj < 13; ++jj) {
      if (jj < jcnt) {
        const int j = jstart + jj;
        const float e = expf(tvv[jj] - mx);
        s += e; sy += e*(float)(j/7 - RR); sx += e*(float)(j%7 - RR);
      }
    }
    float* pp = &ldsf[PBASE + (wv*64 + px)*4];
    pp[0] = mx; pp[1] = s; pp[2] = sy; pp[3] = sx;
  }
  BARRIER();

  // ---- epilogue phase 4: combine wave partials (wave 0), write outputs ----
  if (wv == 0) {
    const int px = lane, rr = px >> 4, cc = px & 15;
    float M[4], S[4], SY[4], SX[4];
    #pragma unroll
    for (int w = 0; w < 4; ++w) {
      const float* pp = &ldsf[PBASE + (w*64 + px)*4];
      M[w] = pp[0]; S[w] = pp[1]; SY[w] = pp[2]; SX[w] = pp[3];
    }
    float m = fmaxf(fmaxf(M[0], M[1]), fmaxf(M[2], M[3]));
    float s = 0.f, sy = 0.f, sx = 0.f;
    #pragma unroll
    for (int w = 0; w < 4; ++w) {
      const float f = expf(M[w] - m);
      s += S[w]*f; sy += SY[w]*f; sx += SX[w]*f;
    }
    const float inv_s = 1.f / s;         // conf_local = exp(mx-mx)/s at the argmax
    const int n = (tileY*TSY + rr)*NW + tileX*TSX + cc;
    const int gg = b*NPIX + n;
    dyl[gg] = sy * inv_s;
    dxl[gg] = sx * inv_s;
    out[(size_t)2*NB*NPIX + gg] = inv_s;                       // conf_local
    const float lw = fminf(fmaxf((inv_s - UNI)/(1.f-UNI), 0.f), 1.f);
    out[(size_t)3*NB*NPIX + 4 + gg] = lw;                      // lw
  }
}

// ---------------- kernel E: global softmax (per-block recompute) + blend + smooth ----------------
__global__ __launch_bounds__(256) void smooth_global(
    const float* __restrict__ dyl, const float* __restrict__ dxl,
    const float* __restrict__ gacc, float* __restrict__ out,
    const int* __restrict__ hvisp, const int* __restrict__ wvisp) {
  __shared__ float sh[2];
  const int g = blockIdx.x*256 + threadIdx.x;
  const int b = g / NPIX, n = g % NPIX;
  const int h = n / NW, w = n % NW;

  // wave 0 recomputes this batch's global softmax (deterministic, identical across blocks)
  if (threadIdx.x < 64) {
    const int k = threadIdx.x;
    float t = -1e30f;
    if (k < NK) {
      float ssum = 0.f;
      for (int i = 0; i < 144; ++i) ssum += gacc[((size_t)b*NK + k)*144 + i];
      t = ssum * (1.f / (float)NPIX);
    }
    float m = t;
    #pragma unroll
    for (int msk = 1; msk < 64; msk <<= 1) m = fmaxf(m, __shfl_xor(m, msk));
    const float e = (k < NK) ? expf(t - m) : 0.f;
    const float dyv = (k < NK) ? (float)(k/7 - RR) : 0.f;
    const float dxv = (k < NK) ? (float)(k%7 - RR) : 0.f;
    float s = e, sy = e*dyv, sx = e*dxv;
    #pragma unroll
    for (int msk = 1; msk < 64; msk <<= 1) {
      s  += __shfl_xor(s,  msk);
      sy += __shfl_xor(sy, msk);
      sx += __shfl_xor(sx, msk);
    }
    if (k == 0) {
      out[(size_t)3*NB*NPIX + b] = 1.f / s;   // conf_global (same value from all 36 blocks of b)
      sh[0] = sy / s;                          // dy_global
      sh[1] = sx / s;                          // dx_global
    }
  }
  __syncthreads();
  const float dyg = sh[0], dxg = sh[1];

  const float* conf = out + (size_t)2*NB*NPIX;
  float sy = 0.f, sx = 0.f;
  #pragma unroll
  for (int ddy = -1; ddy <= 1; ++ddy)
    #pragma unroll
    for (int ddx = -1; ddx <= 1; ++ddx) {
      const int hh = h + ddy, wc = w + ddx;
      if (hh >= 0 && hh < NH && wc >= 0 && wc < NW) {   // zero padding
        const int q2 = b*NPIX + hh*NW + wc;
        const float cf = conf[q2];
        const float lw = fminf(fmaxf((cf - UNI)/(1.f-UNI), 0.f), 1.f);
        sy += lw*dyl[q2] + (1.f-lw)*dyg;
        sx += lw*dxl[q2] + (1.f-lw)*dxg;
      }
    }
  const float skyy = (float)hvisp[0] * 0.1f / (float)NH;
  const float skyx = (float)wvisp[0] * 0.1f / (float)NW;
  out[g] = sx * (1.f/9.f) * skyx;                     // dra
  out[(size_t)NB*NPIX + g] = sy * (1.f/9.f) * skyy;   // ddec
}

// ---------------- host launch ----------------
extern "C" void kernel_launch(void* const* d_in, const int* in_sizes, int n_in,
                              void* d_out, int out_size, void* d_ws, size_t ws_size,
                              hipStream_t stream) {
  (void)in_sizes; (void)n_in; (void)out_size; (void)ws_size;
  const float* rubin = (const float*)d_in[0];
  const float* vis   = (const float*)d_in[1];
  const int* hvis = (const int*)d_in[4];
  const int* wvis = (const int*)d_in[5];
  float* out = (float*)d_out;

  float* dyl  = (float*)d_ws;                       // NB*NPIX
  float* dxl  = dyl  + (size_t)NB*NPIX;             // NB*NPIX
  float* gacc = dxl  + (size_t)NB*NPIX;             // NB*49*144

  corr_fused<<<dim3(576), 256, 0, stream>>>(rubin, vis, dyl, dxl, gacc, out);
  smooth_global<<<dim3((NB*NPIX)/256), 256, 0, stream>>>(dyl, dxl, gacc, out, hvis, wvis);
}

// Round 13
// 67.264 us; speedup vs baseline: 6.4822x; 1.1639x over previous
//
#include <hip/hip_runtime.h>
#include <hip/hip_bf16.h>
#include <math.h>

// ---------------- problem constants ----------------
#define NB 4
#define NH 96
#define NW 96
#define ND 768
#define NPIX (NH*NW)          // 9216
#define RR 3
#define NK 49
#define DCC 32                // K per staged chunk
#define NCH 24                // 768/32 — full K per block (fused, NS=1)
#define TSX 16                // tile 16 wide
#define TSY 4                 //        4 tall (wave per row)
#define HLX 22                // halo 22 wide
#define HLY 10                // halo 10 tall
#define NVIS (HLX*HLY)        // 220
#define VPAD 224              // vis region padded to multiple of 32
#define NSLOT (VPAD+64)       // 288 (224 vis+dummy, 64 rubin)
#define LROW 40               // ushorts per slot (32 bf16 + 8 pad = 80B)
#define NPASS 9               // 288 slots * 8 lanes / 256 threads
#define TPX 65                // transpose row stride (floats) — conflict-free
#define TBASE 512             // transpose region base (floats)
#define PBASE 4680            // softmax partials region base (floats)
#define TAU 0.1f
#define SCALE 0.03608439182435161f  // 1/sqrt(768)
#define UNI (1.0f/49.0f)

typedef float f32x4 __attribute__((ext_vector_type(4)));
typedef short bfx8 __attribute__((ext_vector_type(8)));

__device__ __forceinline__ unsigned pk2(float lo, float hi) {
  __hip_bfloat162 h = __float22bfloat162_rn(make_float2(lo, hi));  // v_cvt_pk_bf16_f32
  unsigned u; __builtin_memcpy(&u, &h, 4);
  return u;
}

// barrier that waits LDS ops only (no vmcnt drain — prefetch stays in flight)
#define BARRIER() do { asm volatile("s_waitcnt lgkmcnt(0)" ::: "memory"); \
                       __builtin_amdgcn_s_barrier(); } while (0)

// ws layout: dyl, dxl : float [b][NPIX] ; gacc : float [b][49][144]
// out: dra | ddec | conf_local | conf_global[4] | lw

// ---------------- fused kernel: MFMA correlation + norms + local softmax ----------------
// Register budget note (r11 lesson): __launch_bounds__ 2nd arg is min waves/SIMD.
// 2 -> ~256-reg unified cap; 3 -> ~170; 4 -> 128. 2-deep prefetch (r12) needs ~164
// regs -> only fits at 2 waves/SIMD (2 blocks/CU). This round: 1-deep prefetch
// (~128 regs) at 3 waves/SIMD -> 3 blocks/CU (12 waves/CU TLP). Spill signature to
// watch: VGPR_Count==64 + WRITE_SIZE in the tens of MB (r8/r11).
__global__ __launch_bounds__(256, 3) void corr_fused(
    const float* __restrict__ rubin, const float* __restrict__ vis,
    float* __restrict__ dyl, float* __restrict__ dxl,
    float* __restrict__ gacc, float* __restrict__ out) {
  __shared__ __align__(16) unsigned short lds[NSLOT*LROW];  // 23,040 B (float view: 5760)
  float* ldsf = (float*)lds;
  const int tid = threadIdx.x;

  // ---- XCD-chunked swizzle: each XCD owns 72 contiguous (b,ty,tx) slots ----
  const int wg = blockIdx.x;                  // 0..575
  const int vs = (wg & 7) * 72 + (wg >> 3);   // bijective (576 = 8*72)
  const int b = vs / 144, t = vs % 144;
  const int tileY = t / 6, tileX = t % 6;

  const int g8 = tid >> 3, q = tid & 7;       // 32 slots/pass, 8 lanes/slot

  // ---- staging slot -> global element offset ----
  unsigned voff[NPASS]; int lws[NPASS];
  #pragma unroll
  for (int p = 0; p < NPASS; ++p) {
    const int s = p*32 + g8;
    lws[p] = s*LROW + q*4;
    unsigned pix = 0;
    if (p < 7) {                                 // vis halo (or dummy)
      const int vy = s / HLX, vx = s % HLX;
      const int gh = min(max(tileY*TSY + vy - RR, 0), NH-1);
      const int gw = min(max(tileX*TSX + vx - RR, 0), NW-1);
      pix = (unsigned)(b*NPIX + gh*NW + gw);
    } else {                                     // rubin
      const int ridx = s - VPAD;
      pix = (unsigned)(b*NPIX + (tileY*TSY + (ridx >> 4))*NW + tileX*TSX + (ridx & 15));
    }
    voff[p] = pix*ND + (unsigned)(q*4);
  }
  #define ACT(p) ((p) != 6 || g8 < 28)

  // ---- MFMA addressing: wave wv owns tile row wv ----
  const int lane = tid & 63, wv = tid >> 6;
  const int j15 = lane & 15, kq = lane >> 4;
  const int aOff = (VPAD + wv*TSX + j15)*LROW + kq*8;
  const int bO0 = j15*LROW + kq*8;
  const int bO1 = min(j15 + 16, HLX-1)*LROW + kq*8;

  f32x4 acc[7][2];
  #pragma unroll
  for (int dy = 0; dy < 7; ++dy) {
    acc[dy][0] = (f32x4){0.f,0.f,0.f,0.f};
    acc[dy][1] = (f32x4){0.f,0.f,0.f,0.f};
  }
  float ssq[NPASS];
  #pragma unroll
  for (int p = 0; p < NPASS; ++p) ssq[p] = 0.f;

#define LOADCH(Larr, chv) { \
  _Pragma("unroll") \
  for (int p = 0; p < NPASS; ++p) if (ACT(p)) \
    Larr[p] = (p < 7) ? *(const float4*)(vis   + voff[p] + (chv)*DCC) \
                      : *(const float4*)(rubin + voff[p] + (chv)*DCC); }

#define WRITECH(Larr) { \
  _Pragma("unroll") \
  for (int p = 0; p < NPASS; ++p) if (ACT(p)) { \
    const float4 v = Larr[p]; \
    ssq[p] += v.x*v.x + v.y*v.y + v.z*v.z + v.w*v.w; \
    *(uint2*)&lds[lws[p]] = make_uint2(pk2(v.x,v.y), pk2(v.z,v.w)); } }

#define MFMACH() { \
  const bfx8 A = *(const bfx8*)&lds[aOff]; \
  _Pragma("unroll") \
  for (int dy = 0; dy < 7; ++dy) { \
    const int rbase = (wv + dy)*HLX*LROW; \
    const bfx8 B0 = *(const bfx8*)&lds[rbase + bO0]; \
    const bfx8 B1 = *(const bfx8*)&lds[rbase + bO1]; \
    acc[dy][0] = __builtin_amdgcn_mfma_f32_16x16x32_bf16(A, B0, acc[dy][0], 0, 0, 0); \
    acc[dy][1] = __builtin_amdgcn_mfma_f32_16x16x32_bf16(A, B1, acc[dy][1], 0, 0, 0); } }

  // ---- 1-deep software pipeline: load ch+1 in flight across MFMA phase ----
  float4 L[NPASS];
  LOADCH(L, 0);
  for (int ch = 0; ch < NCH; ++ch) {
    if (ch) BARRIER();            // prev chunk's MFMA readers done
    WRITECH(L);
    BARRIER();
    if (ch + 1 < NCH) LOADCH(L, ch + 1);   // in flight during MFMA + next barrier
    MFMACH();
  }
  BARRIER();   // all MFMA LDS reads done before epilogue clobbers lds

  // ---- epilogue phase 1: per-slot sum-of-squares into ldsf[0..287] ----
  #pragma unroll
  for (int p = 0; p < NPASS; ++p) {
    float r = ACT(p) ? ssq[p] : 0.f;
    r += __shfl_xor(r, 1); r += __shfl_xor(r, 2); r += __shfl_xor(r, 4);
    if (q == 0 && ACT(p)) ldsf[p*32 + g8] = r;
  }
  BARRIER();

  // ---- epilogue phase 2: transpose C-fragments -> ldsf[TBASE + px*TPX + j] ----
  #pragma unroll
  for (int dy = 0; dy < 7; ++dy)
    #pragma unroll
    for (int h = 0; h < 2; ++h)
      #pragma unroll
      for (int r = 0; r < 4; ++r) {
        const int i = kq*4 + r;
        const int dxp3 = h ? (j15 + 16 - i) : (j15 - i);
        if (dxp3 >= 0 && dxp3 < 7)
          ldsf[TBASE + (wv*TSX + i)*TPX + dy*7 + dxp3] = acc[dy][h][r];
      }
  BARRIER();

  // ---- epilogue phase 3: wave-parallel softmax (wave wv owns 12-13 taps) ----
  {
    const int px = lane, rr = px >> 4, cc = px & 15;     // 64 pixels, all waves
    const float irf = (SCALE/TAU) / fmaxf(sqrtf(ldsf[VPAD + px]), 1e-6f);
    const int jstart = wv*12 + (wv > 0 ? 1 : 0);         // 13,12,12,12 taps
    const int jcnt = (wv == 0) ? 13 : 12;
    float tvv[13];
    float mx = -1e30f;
    #pragma unroll
    for (int jj = 0; jj < 13; ++jj) {
      if (jj < jcnt) {
        const int j = jstart + jj;
        const int jy = j / 7, jx = j % 7;
        const float c = ldsf[TBASE + px*TPX + j];
        const float iv = 1.f / fmaxf(sqrtf(ldsf[(rr+jy)*HLX + cc + jx]), 1e-6f);
        const float tv = c * irf * iv;
        tvv[jj] = tv;
        mx = fmaxf(mx, tv);
        float red = tv;                                   // tile-sum for global softmax
        #pragma unroll
        for (int m = 1; m < 64; m <<= 1) red += __shfl_xor(red, m);
        if (lane == 0) gacc[((size_t)b*NK + j)*144 + t] = red;
      } else tvv[jj] = -1e30f;
    }
    float s = 0.f, sy = 0.f, sx = 0.f;
    #pragma unroll
    for (int jj = 0; jj < 13; ++jj) {
      if (jj < jcnt) {
        const int j = jstart + jj;
        const float e = expf(tvv[jj] - mx);
        s += e; sy += e*(float)(j/7 - RR); sx += e*(float)(j%7 - RR);
      }
    }
    float* pp = &ldsf[PBASE + (wv*64 + px)*4];
    pp[0] = mx; pp[1] = s; pp[2] = sy; pp[3] = sx;
  }
  BARRIER();

  // ---- epilogue phase 4: combine wave partials (wave 0), write outputs ----
  if (wv == 0) {
    const int px = lane, rr = px >> 4, cc = px & 15;
    float M[4], S[4], SY[4], SX[4];
    #pragma unroll
    for (int w = 0; w < 4; ++w) {
      const float* pp = &ldsf[PBASE + (w*64 + px)*4];
      M[w] = pp[0]; S[w] = pp[1]; SY[w] = pp[2]; SX[w] = pp[3];
    }
    float m = fmaxf(fmaxf(M[0], M[1]), fmaxf(M[2], M[3]));
    float s = 0.f, sy = 0.f, sx = 0.f;
    #pragma unroll
    for (int w = 0; w < 4; ++w) {
      const float f = expf(M[w] - m);
      s += S[w]*f; sy += SY[w]*f; sx += SX[w]*f;
    }
    const float inv_s = 1.f / s;         // conf_local = exp(mx-mx)/s at the argmax
    const int n = (tileY*TSY + rr)*NW + tileX*TSX + cc;
    const int gg = b*NPIX + n;
    dyl[gg] = sy * inv_s;
    dxl[gg] = sx * inv_s;
    out[(size_t)2*NB*NPIX + gg] = inv_s;                       // conf_local
    const float lw = fminf(fmaxf((inv_s - UNI)/(1.f-UNI), 0.f), 1.f);
    out[(size_t)3*NB*NPIX + 4 + gg] = lw;                      // lw
  }
}

// ---------------- kernel E: global softmax (per-block recompute) + blend + smooth ----------------
__global__ __launch_bounds__(256) void smooth_global(
    const float* __restrict__ dyl, const float* __restrict__ dxl,
    const float* __restrict__ gacc, float* __restrict__ out,
    const int* __restrict__ hvisp, const int* __restrict__ wvisp) {
  __shared__ float sh[2];
  const int g = blockIdx.x*256 + threadIdx.x;
  const int b = g / NPIX, n = g % NPIX;
  const int h = n / NW, w = n % NW;

  // wave 0 recomputes this batch's global softmax (deterministic, identical across blocks)
  if (threadIdx.x < 64) {
    const int k = threadIdx.x;
    float t = -1e30f;
    if (k < NK) {
      float ssum = 0.f;
      for (int i = 0; i < 144; ++i) ssum += gacc[((size_t)b*NK + k)*144 + i];
      t = ssum * (1.f / (float)NPIX);
    }
    float m = t;
    #pragma unroll
    for (int msk = 1; msk < 64; msk <<= 1) m = fmaxf(m, __shfl_xor(m, msk));
    const float e = (k < NK) ? expf(t - m) : 0.f;
    const float dyv = (k < NK) ? (float)(k/7 - RR) : 0.f;
    const float dxv = (k < NK) ? (float)(k%7 - RR) : 0.f;
    float s = e, sy = e*dyv, sx = e*dxv;
    #pragma unroll
    for (int msk = 1; msk < 64; msk <<= 1) {
      s  += __shfl_xor(s,  msk);
      sy += __shfl_xor(sy, msk);
      sx += __shfl_xor(sx, msk);
    }
    if (k == 0) {
      out[(size_t)3*NB*NPIX + b] = 1.f / s;   // conf_global (same value from all 36 blocks of b)
      sh[0] = sy / s;                          // dy_global
      sh[1] = sx / s;                          // dx_global
    }
  }
  __syncthreads();
  const float dyg = sh[0], dxg = sh[1];

  const float* conf = out + (size_t)2*NB*NPIX;
  float sy = 0.f, sx = 0.f;
  #pragma unroll
  for (int ddy = -1; ddy <= 1; ++ddy)
    #pragma unroll
    for (int ddx = -1; ddx <= 1; ++ddx) {
      const int hh = h + ddy, wc = w + ddx;
      if (hh >= 0 && hh < NH && wc >= 0 && wc < NW) {   // zero padding
        const int q2 = b*NPIX + hh*NW + wc;
        const float cf = conf[q2];
        const float lw = fminf(fmaxf((cf - UNI)/(1.f-UNI), 0.f), 1.f);
        sy += lw*dyl[q2] + (1.f-lw)*dyg;
        sx += lw*dxl[q2] + (1.f-lw)*dxg;
      }
    }
  const float skyy = (float)hvisp[0] * 0.1f / (float)NH;
  const float skyx = (float)wvisp[0] * 0.1f / (float)NW;
  out[g] = sx * (1.f/9.f) * skyx;                     // dra
  out[(size_t)NB*NPIX + g] = sy * (1.f/9.f) * skyy;   // ddec
}

// ---------------- host launch ----------------
extern "C" void kernel_launch(void* const* d_in, const int* in_sizes, int n_in,
                              void* d_out, int out_size, void* d_ws, size_t ws_size,
                              hipStream_t stream) {
  (void)in_sizes; (void)n_in; (void)out_size; (void)ws_size;
  const float* rubin = (const float*)d_in[0];
  const float* vis   = (const float*)d_in[1];
  const int* hvis = (const int*)d_in[4];
  const int* wvis = (const int*)d_in[5];
  float* out = (float*)d_out;

  float* dyl  = (float*)d_ws;                       // NB*NPIX
  float* dxl  = dyl  + (size_t)NB*NPIX;             // NB*NPIX
  float* gacc = dxl  + (size_t)NB*NPIX;             // NB*49*144

  corr_fused<<<dim3(576), 256, 0, stream>>>(rubin, vis, dyl, dxl, gacc, out);
  smooth_global<<<dim3((NB*NPIX)/256), 256, 0, stream>>>(dyl, dxl, gacc, out, hvis, wvis);
}